// Round 4
// baseline (5708.905 us; speedup 1.0000x reference)
//
#include <hip/hip_runtime.h>

// ---------------------------------------------------------------------------
// LSTM (B=128, T=512, D=512, H=1024, O=256), forget bias 1.0
//   prep:    f16 conversions/transposes/fragment-packing of weights
//   phase1:  xw = X @ W_x + b  (f16 MFMA GEMM, 65536x512x4096) -> ws
//   phase2:  persistent cooperative kernel, 512 sequential steps.
//            8 teams x 16 batch rows; 32 blocks/team each owning 32 hidden
//            units (128 gate cols). W_h fragments live in VGPRs.
//            Sync protocol (per step): producer waves store h (sc0 sc1,
//            IF$-coherent), drain own store, atomically bump a per-block
//            counter; consumer WAVES each poll only their 8 producer blocks
//            and stage only their own K-slice via global_load_lds (sc0 sc1).
//            No block-wide poll, no threadfence, bulk stores off the path.
//   phase3:  logits = lstm_out @ W_out + b_out (f16 MFMA GEMM)
// ---------------------------------------------------------------------------

typedef _Float16 f16;
typedef _Float16 half8 __attribute__((ext_vector_type(8)));
typedef float floatx4 __attribute__((ext_vector_type(4)));

#define AS1 __attribute__((address_space(1)))
#define AS3 __attribute__((address_space(3)))

__device__ __forceinline__ void gload_lds16(const void* g, void* l) {
  __builtin_amdgcn_global_load_lds((const AS1 void*)g, (AS3 void*)l, 16, 0, 0);
}
// coherent (device-scope) variant: aux = SC0|SC1 = 1|16
__device__ __forceinline__ void gload_lds16_coh(const void* g, void* l) {
  __builtin_amdgcn_global_load_lds((const AS1 void*)g, (AS3 void*)l, 16, 0, 17);
}

__device__ __forceinline__ int load_flag_coh(const unsigned* p) {
  int v;
  asm volatile("global_load_dword %0, %1, off sc0 sc1\n\ts_waitcnt vmcnt(0)"
               : "=v"(v) : "v"(p) : "memory");
  return v;
}
__device__ __forceinline__ void store_h_coh(f16* p, f16 v) {
  unsigned int uv = (unsigned int)__builtin_bit_cast(unsigned short, v);
  asm volatile("global_store_short %0, %1, off sc0 sc1" :: "v"(p), "v"(uv) : "memory");
}

__device__ __forceinline__ float sigm(float x) { return 1.f / (1.f + __expf(-x)); }
__device__ __forceinline__ float tanh_fast(float x) {
  float ax = fabsf(x);
  float e = __expf(2.f * ax);          // overflows to +inf for big |x| -> t=1 exactly
  float t = 1.f - 2.f / (e + 1.f);
  return copysignf(t, x);
}

// ---------------- workspace layout ----------------
static constexpr size_t XW_OFF  = 0;
static constexpr size_t XW_BY   = (size_t)65536 * 4096 * 2;        // 536870912
static constexpr size_t L16_OFF = XW_OFF + XW_BY;                  // lstm_out f16 (aliases in16)
static constexpr size_t L16_BY  = (size_t)65536 * 1024 * 2;        // 134217728
static constexpr size_t IN16_OFF = L16_OFF;                        // inputs f16 (phase1 only)
static constexpr size_t WXT_OFF = L16_OFF + L16_BY;
static constexpr size_t WXT_BY  = (size_t)4096 * 512 * 2;
static constexpr size_t WOT_OFF = WXT_OFF + WXT_BY;
static constexpr size_t WOT_BY  = (size_t)256 * 1024 * 2;
static constexpr size_t WPK_OFF = WOT_OFF + WOT_BY;
static constexpr size_t WPK_BY  = (size_t)524288 * 8 * 2;          // W_h frag-packed
static constexpr size_t TH_OFF  = WPK_OFF + WPK_BY;
static constexpr size_t TH_BY   = (size_t)2 * 128 * 1024 * 2;      // h ping-pong (f16)
static constexpr size_t FLG_OFF = TH_OFF + TH_BY;
static constexpr size_t FLG_BY  = (size_t)8 * 32 * 4;              // counters[team][block]
static constexpr size_t WS_NEED = FLG_OFF + FLG_BY;

// ---------------- prep kernels ----------------
__global__ __launch_bounds__(256) void conv_f32_to_f16(const float* __restrict__ in,
                                                       f16* __restrict__ out) {
  size_t i = (size_t)blockIdx.x * 256 + threadIdx.x;
  const float4* in4 = (const float4*)in;
  float4 a = in4[i * 2], b = in4[i * 2 + 1];
  half8 v = {(f16)a.x, (f16)a.y, (f16)a.z, (f16)a.w,
             (f16)b.x, (f16)b.y, (f16)b.z, (f16)b.w};
  *(half8*)(out + i * 8) = v;
}

// out[c][r] = (f16)in[r][c]; grid = (C/64, R/64)
__global__ __launch_bounds__(256) void transpose_f32_to_f16(const float* __restrict__ in,
                                                            f16* __restrict__ out,
                                                            int R, int C) {
  __shared__ float tile[64][65];
  int tx = threadIdx.x & 63, ty = threadIdx.x >> 6;
  int c0 = blockIdx.x * 64, r0 = blockIdx.y * 64;
#pragma unroll
  for (int q = 0; q < 16; ++q) {
    int r = q * 4 + ty;
    tile[r][tx] = in[(size_t)(r0 + r) * C + c0 + tx];
  }
  __syncthreads();
#pragma unroll
  for (int q = 0; q < 16; ++q) {
    int oc = q * 4 + ty;
    out[(size_t)(c0 + oc) * R + r0 + tx] = (f16)tile[tx][oc];
  }
}

// Pack W_h (rows 512..1535 of W_lstm) into per-(colblock,wave,ni,ks,lane) f16x8
// fragments matching the phase-2 MFMA B-operand layout (n=lane&15, k=(lane>>4)*8+e).
__global__ __launch_bounds__(256) void pack_wh(const float* __restrict__ W,
                                               f16* __restrict__ wpack) {
  int s = blockIdx.x * 256 + threadIdx.x;   // 0 .. 524287
  int lane = s & 63;
  int ks = (s >> 6) & 7;
  int ni = (s >> 9) & 3;
  int w  = (s >> 11) & 7;
  int cb = s >> 14;                          // 0..31
  int nh = w & 1, ksl = w >> 1;
  int c = nh * 64 + ni * 16 + (lane & 15);   // block-local col 0..127
  int g = c >> 5, ul = c & 31;
  int ncol = g * 1024 + cb * 32 + ul;        // global gate col
  int kb = ksl * 256 + ks * 32 + (lane >> 4) * 8;
  half8 v;
#pragma unroll
  for (int e = 0; e < 8; ++e)
    v[e] = (f16)W[(size_t)(512 + kb + e) * 4096 + ncol];
  ((half8*)wpack)[s] = v;
}

// ---------------- generic f16 MFMA GEMM: C = A[MxK] * Bt[NxK]^T + bias ----------------
template <typename OT>
__global__ __launch_bounds__(256) void gemm_f16(const f16* __restrict__ A,
                                                const f16* __restrict__ Bt,
                                                const float* __restrict__ bias,
                                                OT* __restrict__ C,
                                                int M, int N, int K) {
  __shared__ __align__(16) char smem[32768];   // As 16K | Bs 16K
  const int tid = threadIdx.x;
  const int n0 = blockIdx.x * 128, m0 = blockIdx.y * 128;
  const int l = tid & 63, w = tid >> 6;
  const int wr = w >> 1, wc = w & 1;
  const int r16 = l & 15, hi = l >> 4;
  floatx4 acc[4][4];
#pragma unroll
  for (int a = 0; a < 4; ++a)
#pragma unroll
    for (int b = 0; b < 4; ++b) acc[a][b] = (floatx4){0.f, 0.f, 0.f, 0.f};

  const int nk = K >> 6;
  for (int kk = 0; kk < nk; ++kk) {
    __syncthreads();
#pragma unroll
    for (int q = 0; q < 4; ++q) {
      int c = q * 256 + tid;
      int row = c >> 3, g8 = c & 7;
      gload_lds16(A + (size_t)(m0 + row) * K + kk * 64 + g8 * 8, smem + c * 16);
    }
#pragma unroll
    for (int q = 0; q < 4; ++q) {
      int c = q * 256 + tid;
      int row = c >> 3, g8 = c & 7;
      gload_lds16(Bt + (size_t)(n0 + row) * K + kk * 64 + g8 * 8, smem + 16384 + c * 16);
    }
    __syncthreads();
#pragma unroll
    for (int ks = 0; ks < 2; ++ks) {
      half8 af[4], bf[4];
#pragma unroll
      for (int mi = 0; mi < 4; ++mi)
        af[mi] = *(const half8*)(smem + ((wr * 64 + mi * 16 + r16) * 64 + ks * 32 + hi * 8) * 2);
#pragma unroll
      for (int ni = 0; ni < 4; ++ni)
        bf[ni] = *(const half8*)(smem + 16384 +
                                 ((wc * 64 + ni * 16 + r16) * 64 + ks * 32 + hi * 8) * 2);
#pragma unroll
      for (int mi = 0; mi < 4; ++mi)
#pragma unroll
        for (int ni = 0; ni < 4; ++ni)
          acc[mi][ni] = __builtin_amdgcn_mfma_f32_16x16x32_f16(af[mi], bf[ni], acc[mi][ni], 0, 0, 0);
    }
  }
#pragma unroll
  for (int ni = 0; ni < 4; ++ni) {
    int col = n0 + wc * 64 + ni * 16 + r16;
    float bv = bias[col];
#pragma unroll
    for (int mi = 0; mi < 4; ++mi)
#pragma unroll
      for (int rr = 0; rr < 4; ++rr) {
        int row = m0 + wr * 64 + mi * 16 + hi * 4 + rr;
        C[(size_t)row * N + col] = (OT)(acc[mi][ni][rr] + bv);
      }
  }
}

// ---------------- phase 2: persistent recurrent kernel ----------------
// grid 256 blocks x 512 threads. block bk: team = bk>>5 (16 batch rows),
// colblock cb = bk&31 (hidden units u0..u0+31 -> gate cols {g*1024+u0+ul}).
// wave w: ksl = w>>1 (K slice of 256 units), nh = w&1 (64-col half).
// LDS h layout is SLICE-MAJOR: storage granule S = ksl*512 + row*32 + qs,
// slot qs holds logical 8-unit group q = qs ^ (row&7) of slice ksl.
__global__ __launch_bounds__(512, 2)
void lstm_phase2(const f16* __restrict__ wpack, const f16* __restrict__ xw,
                 const float* __restrict__ c_in, const float* __restrict__ h_in,
                 const int* __restrict__ seq_lens,
                 f16* teamh, unsigned* flags,
                 float* __restrict__ lstm_out, f16* __restrict__ lstm16,
                 float* __restrict__ c_out, float* __restrict__ h_out) {
  __shared__ __align__(16) char smem[65536];   // h slices 32K | red 32K (XOR-swizzled)
  const int tid = threadIdx.x;
  const int bk = blockIdx.x;
  const int team = bk >> 5, cb = bk & 31;
  const int b0 = team * 16;
  const int u0 = cb * 32;
  const int l = tid & 63, w = tid >> 6;
  const int nh = w & 1, ksl = w >> 1;
  const int r16 = l & 15, hi = l >> 4;

  // persistent W_h fragments: 32 x f16x8 = 128 VGPRs
  half8 wf[4][8];
  {
    const half8* wp = (const half8*)wpack;
    size_t base = (size_t)((cb * 8 + w) * 4) * 8 * 64;
#pragma unroll
    for (int ni = 0; ni < 4; ++ni)
#pragma unroll
      for (int ks = 0; ks < 8; ++ks)
        wf[ni][ks] = wp[base + (size_t)(ni * 8 + ks) * 64 + l];
  }

  const int bb = tid >> 5, ul = tid & 31;     // consumer identity: batch row, unit
  const int bglob = b0 + bb;
  const int nunit = u0 + ul;
  float creg = c_in[bglob * 1024 + nunit];
  float hreg = h_in[bglob * 1024 + nunit];
  const int slen = seq_lens[bglob];

  float* red = (float*)(smem + 32768);
  unsigned* myflag = flags + team * 32 + cb;                 // this block's counter
  const unsigned* pollf = flags + team * 32 + ksl * 8 + (l & 7);  // my wave's 8 producers

#pragma unroll 1
  for (int t = 0; t < 512; ++t) {
    // x-projection for this step (plain cached loads; consumed at reduce)
    f16 xwv0, xwv1, xwv2, xwv3;
    {
      const f16* xp = xw + ((size_t)bglob * 512 + t) * 4096 + nunit;
      xwv0 = xp[0]; xwv1 = xp[1024]; xwv2 = xp[2048]; xwv3 = xp[3072];
    }

    if (t > 0) {
      // per-wave poll: lanes 0-7 watch the 8 producer-block counters of slice ksl
      const int tgt = 8 * t;
      while (true) {
        int g = load_flag_coh(pollf);
        if (__all((l >= 8) || (g >= tgt))) break;
        __builtin_amdgcn_s_sleep(1);
      }
      asm volatile("" ::: "memory");
      // per-wave stage: 8 KB slice (rows nh*8..nh*8+7 x 256 units), linear LDS
      // dest + inverse-swizzled coherent source
      const char* hb = (const char*)teamh + (size_t)(t & 1) * (131072 * 2);
#pragma unroll
      for (int j = 0; j < 4; ++j) {
        int rj = nh * 8 + 2 * j + (l >> 5);
        int ql = (l & 31) ^ (rj & 7);
        gload_lds16_coh(hb + ((size_t)(b0 + rj) * 1024 + ksl * 256 + ql * 8) * 2,
                        smem + (ksl * 512 + (nh * 8 + 2 * j) * 32) * 16);
      }
      asm volatile("s_waitcnt vmcnt(0)" ::: "memory");   // own slice landed in LDS
    } else {
      // first step: stage h_in (fp32 -> f16) into the same slice-major layout
#pragma unroll
      for (int j = 0; j < 4; ++j) {
        int idx = j * 512 + tid;            // storage granule 0..2047
        int ks_s = idx >> 9, rem = idx & 511, r = rem >> 5, qs = rem & 31;
        int ql = qs ^ (r & 7);
        const float* s = h_in + (size_t)(b0 + r) * 1024 + ks_s * 256 + ql * 8;
        half8 v;
#pragma unroll
        for (int e = 0; e < 8; ++e) v[e] = (f16)s[e];
        *(half8*)(smem + idx * 16) = v;
      }
    }
    __syncthreads();                     // bar D: all slices staged

    // MFMA: gates_partial[16 x 64cols] over K slice of 256
    floatx4 acc0 = {0.f, 0.f, 0.f, 0.f}, acc1 = acc0, acc2 = acc0, acc3 = acc0;
#pragma unroll
    for (int ks = 0; ks < 8; ++ks) {
      int pq = (ks * 4 + hi) ^ (r16 & 7);       // swizzled slot -> conflict-free b128
      half8 a = *(const half8*)(smem + ksl * 8192 + r16 * 512 + pq * 16);
      acc0 = __builtin_amdgcn_mfma_f32_16x16x32_f16(a, wf[0][ks], acc0, 0, 0, 0);
      acc1 = __builtin_amdgcn_mfma_f32_16x16x32_f16(a, wf[1][ks], acc1, 0, 0, 0);
      acc2 = __builtin_amdgcn_mfma_f32_16x16x32_f16(a, wf[2][ks], acc2, 0, 0, 0);
      acc3 = __builtin_amdgcn_mfma_f32_16x16x32_f16(a, wf[3][ks], acc3, 0, 0, 0);
    }
    {
      int cbase = nh * 64 + r16;
      int rbase = ksl * 16 + hi * 4;
#pragma unroll
      for (int rr = 0; rr < 4; ++rr) {
        int rowr = rbase + rr;
        unsigned sw = (unsigned)(rowr & 7) << 2;   // bank XOR-swizzle
        float* rp = red + (size_t)rowr * 128;
        rp[(cbase + 0) ^ sw]  = acc0[rr];
        rp[(cbase + 16) ^ sw] = acc1[rr];
        rp[(cbase + 32) ^ sw] = acc2[rr];
        rp[(cbase + 48) ^ sw] = acc3[rr];
      }
    }
    __syncthreads();                     // bar G: red complete (also WAR guard)

    // reduce 4 K-slices + x-projection, then gate nonlinearities
    float g0 = (float)xwv0, g1 = (float)xwv1, g2 = (float)xwv2, g3 = (float)xwv3;
#pragma unroll
    for (int p = 0; p < 4; ++p) {
      int rowp = p * 16 + bb;
      unsigned sw = (unsigned)(rowp & 7) << 2;
      const float* rp = red + (size_t)rowp * 128;
      g0 += rp[(ul + 0) ^ sw];
      g1 += rp[(ul + 32) ^ sw];
      g2 += rp[(ul + 64) ^ sw];
      g3 += rp[(ul + 96) ^ sw];
    }
    float nc = creg * sigm(g2 + 1.f) + sigm(g0) * tanh_fast(g1);   // i,j,f,o order
    float nhv = tanh_fast(nc) * sigm(g3);
    bool valid = t < slen;
    if (valid) { creg = nc; hreg = nhv; }
    float outv = valid ? nhv : 0.f;
    size_t orow = ((size_t)bglob * 512 + t) * 1024 + nunit;

    // per-wave publish: coherent h store -> drain (h only) -> counter bump
    store_h_coh(teamh + (size_t)((t + 1) & 1) * 131072 + bglob * 1024 + nunit, (f16)hreg);
    asm volatile("s_waitcnt vmcnt(0)" ::: "memory");
    if (l == 0)
      __hip_atomic_fetch_add(myflag, 1u, __ATOMIC_RELAXED, __HIP_MEMORY_SCOPE_AGENT);
    // bulk outputs: plain cached stores, AFTER the flag (off the critical path)
    lstm_out[orow] = outv;
    lstm16[orow] = (f16)outv;
  }

  c_out[bglob * 1024 + nunit] = creg;
  h_out[bglob * 1024 + nunit] = hreg;
}

// ---------------- host ----------------
extern "C" void kernel_launch(void* const* d_in, const int* in_sizes, int n_in,
                              void* d_out, int out_size, void* d_ws, size_t ws_size,
                              hipStream_t stream) {
  const float* inputs  = (const float*)d_in[0];
  const float* c_in    = (const float*)d_in[1];
  const float* h_in    = (const float*)d_in[2];
  const float* W_lstm  = (const float*)d_in[3];
  const float* b_lstm  = (const float*)d_in[4];
  const float* W_out   = (const float*)d_in[5];
  const float* b_out   = (const float*)d_in[6];
  const int*   seq_lens= (const int*)d_in[7];

  float* logits  = (float*)d_out;
  float* lstm_out= logits + (size_t)65536 * 256;
  float* c_out   = lstm_out + (size_t)65536 * 1024;
  float* h_out   = c_out + (size_t)128 * 1024;

  if (ws_size < WS_NEED) return;   // fail visibly (poison stays) rather than corrupt

  char* ws = (char*)d_ws;
  f16* xw    = (f16*)(ws + XW_OFF);
  f16* in16  = (f16*)(ws + IN16_OFF);
  f16* l16   = (f16*)(ws + L16_OFF);
  f16* wxt   = (f16*)(ws + WXT_OFF);
  f16* wot   = (f16*)(ws + WOT_OFF);
  f16* wpk   = (f16*)(ws + WPK_OFF);
  f16* teamh = (f16*)(ws + TH_OFF);
  unsigned* flags = (unsigned*)(ws + FLG_OFF);

  hipMemsetAsync(flags, 0, FLG_BY, stream);
  conv_f32_to_f16<<<16384, 256, 0, stream>>>(inputs, in16);
  transpose_f32_to_f16<<<dim3(64, 8), 256, 0, stream>>>(W_lstm, wxt, 512, 4096);
  transpose_f32_to_f16<<<dim3(4, 16), 256, 0, stream>>>(W_out, wot, 1024, 256);
  pack_wh<<<2048, 256, 0, stream>>>(W_lstm, wpk);

  // phase 1: xw = X @ W_x + b_lstm
  gemm_f16<f16><<<dim3(32, 512), 256, 0, stream>>>(in16, wxt, b_lstm, xw, 65536, 4096, 512);

  // phase 2: persistent recurrence (cooperative => co-residency guaranteed)
  {
    const f16* wpk_c = wpk;
    const f16* xw_c  = xw;
    void* args[] = {(void*)&wpk_c, (void*)&xw_c, (void*)&c_in, (void*)&h_in,
                    (void*)&seq_lens, (void*)&teamh, (void*)&flags,
                    (void*)&lstm_out, (void*)&l16, (void*)&c_out, (void*)&h_out};
    hipLaunchCooperativeKernel((void*)lstm_phase2, dim3(256), dim3(512), args, 0, stream);
  }

  // phase 3: logits = lstm_out @ W_out + b_out
  gemm_f16<float><<<dim3(2, 512), 256, 0, stream>>>(l16, wot, b_out, logits, 65536, 256, 1024);
}

// Round 5
// 3589.557 us; speedup vs baseline: 1.5904x; 1.5904x over previous
//
#include <hip/hip_runtime.h>

// ---------------------------------------------------------------------------
// LSTM (B=128, T=512, D=512, H=1024, O=256), forget bias 1.0
//   prep:    f16 conversions/transposes/fragment-packing of weights
//   phase1:  xw = X @ W_x + b  (f16 MFMA GEMM, 65536x512x4096) -> ws
//   phase2:  persistent cooperative kernel, 512 sequential steps.
//            8 teams x 16 batch rows; 32 blocks/team each owning 32 hidden
//            units (128 gate cols). W_h fragments live in VGPRs.
//            Sync per step (NO atomics, NO threadfence):
//              producer wave: 64 coherent h stores (sc0 sc1) -> vmcnt(0) ->
//              lane0 PLAIN coherent flag store flags[team][cb][wave]=t+1.
//              consumer wave: 64-lane poll of its 64 producer-wave flags,
//              then stages its own 4KB K-slice via global_load_lds (sc0 sc1).
//            h exchange buffer is 3-deep rotated: writer(t)->buf[(t+1)%3],
//            prior readers of that buf were at t-2, provably finished via the
//            producers' step-(t-1) block barrier (poll union = all 32 blocks).
//   phase3:  logits = lstm_out @ W_out + b_out (f16 MFMA GEMM)
// ---------------------------------------------------------------------------

typedef _Float16 f16;
typedef _Float16 half8 __attribute__((ext_vector_type(8)));
typedef float floatx4 __attribute__((ext_vector_type(4)));

#define AS1 __attribute__((address_space(1)))
#define AS3 __attribute__((address_space(3)))

__device__ __forceinline__ void gload_lds16(const void* g, void* l) {
  __builtin_amdgcn_global_load_lds((const AS1 void*)g, (AS3 void*)l, 16, 0, 0);
}
// coherent (device-scope) variant: aux = SC0|SC1 = 1|16
__device__ __forceinline__ void gload_lds16_coh(const void* g, void* l) {
  __builtin_amdgcn_global_load_lds((const AS1 void*)g, (AS3 void*)l, 16, 0, 17);
}

__device__ __forceinline__ int load_flag_coh(const unsigned* p) {
  int v;
  asm volatile("global_load_dword %0, %1, off sc0 sc1\n\ts_waitcnt vmcnt(0)"
               : "=v"(v) : "v"(p) : "memory");
  return v;
}
__device__ __forceinline__ void store_flag_coh(unsigned* p, unsigned v) {
  asm volatile("global_store_dword %0, %1, off sc0 sc1" :: "v"(p), "v"(v) : "memory");
}
__device__ __forceinline__ void store_h_coh(f16* p, f16 v) {
  unsigned int uv = (unsigned int)__builtin_bit_cast(unsigned short, v);
  asm volatile("global_store_short %0, %1, off sc0 sc1" :: "v"(p), "v"(uv) : "memory");
}

__device__ __forceinline__ float sigm(float x) { return 1.f / (1.f + __expf(-x)); }
__device__ __forceinline__ float tanh_fast(float x) {
  float ax = fabsf(x);
  float e = __expf(2.f * ax);          // overflows to +inf for big |x| -> t=1 exactly
  float t = 1.f - 2.f / (e + 1.f);
  return copysignf(t, x);
}

// ---------------- workspace layout ----------------
static constexpr size_t XW_OFF  = 0;
static constexpr size_t XW_BY   = (size_t)65536 * 4096 * 2;        // 536870912
static constexpr size_t L16_OFF = XW_OFF + XW_BY;                  // lstm_out f16 (aliases in16)
static constexpr size_t L16_BY  = (size_t)65536 * 1024 * 2;        // 134217728
static constexpr size_t IN16_OFF = L16_OFF;                        // inputs f16 (phase1 only)
static constexpr size_t WXT_OFF = L16_OFF + L16_BY;
static constexpr size_t WXT_BY  = (size_t)4096 * 512 * 2;
static constexpr size_t WOT_OFF = WXT_OFF + WXT_BY;
static constexpr size_t WOT_BY  = (size_t)256 * 1024 * 2;
static constexpr size_t WPK_OFF = WOT_OFF + WOT_BY;
static constexpr size_t WPK_BY  = (size_t)524288 * 8 * 2;          // W_h frag-packed
static constexpr size_t TH_OFF  = WPK_OFF + WPK_BY;
static constexpr size_t TH_BY   = (size_t)3 * 4 * 16 * 256 * 2;    // h 3-deep [slice][row][256]
static constexpr size_t FLG_OFF = TH_OFF + (size_t)8 * TH_BY;      // per-team h regions
static constexpr size_t FLG_BY  = (size_t)8 * 32 * 8 * 4;          // flags[team][cb][wave]
static constexpr size_t WS_NEED = FLG_OFF + FLG_BY;

// ---------------- prep kernels ----------------
__global__ __launch_bounds__(256) void conv_f32_to_f16(const float* __restrict__ in,
                                                       f16* __restrict__ out) {
  size_t i = (size_t)blockIdx.x * 256 + threadIdx.x;
  const float4* in4 = (const float4*)in;
  float4 a = in4[i * 2], b = in4[i * 2 + 1];
  half8 v = {(f16)a.x, (f16)a.y, (f16)a.z, (f16)a.w,
             (f16)b.x, (f16)b.y, (f16)b.z, (f16)b.w};
  *(half8*)(out + i * 8) = v;
}

// out[c][r] = (f16)in[r][c]; grid = (C/64, R/64)
__global__ __launch_bounds__(256) void transpose_f32_to_f16(const float* __restrict__ in,
                                                            f16* __restrict__ out,
                                                            int R, int C) {
  __shared__ float tile[64][65];
  int tx = threadIdx.x & 63, ty = threadIdx.x >> 6;
  int c0 = blockIdx.x * 64, r0 = blockIdx.y * 64;
#pragma unroll
  for (int q = 0; q < 16; ++q) {
    int r = q * 4 + ty;
    tile[r][tx] = in[(size_t)(r0 + r) * C + c0 + tx];
  }
  __syncthreads();
#pragma unroll
  for (int q = 0; q < 16; ++q) {
    int oc = q * 4 + ty;
    out[(size_t)(c0 + oc) * R + r0 + tx] = (f16)tile[tx][oc];
  }
}

// Pack W_h (rows 512..1535 of W_lstm) into per-(colblock,wave,ni,ks,lane) f16x8
// fragments matching the phase-2 MFMA B-operand layout (n=lane&15, k=(lane>>4)*8+e).
__global__ __launch_bounds__(256) void pack_wh(const float* __restrict__ W,
                                               f16* __restrict__ wpack) {
  int s = blockIdx.x * 256 + threadIdx.x;   // 0 .. 524287
  int lane = s & 63;
  int ks = (s >> 6) & 7;
  int ni = (s >> 9) & 3;
  int w  = (s >> 11) & 7;
  int cb = s >> 14;                          // 0..31
  int nh = w & 1, ksl = w >> 1;
  int c = nh * 64 + ni * 16 + (lane & 15);   // block-local col 0..127
  int g = c >> 5, ul = c & 31;
  int ncol = g * 1024 + cb * 32 + ul;        // global gate col
  int kb = ksl * 256 + ks * 32 + (lane >> 4) * 8;
  half8 v;
#pragma unroll
  for (int e = 0; e < 8; ++e)
    v[e] = (f16)W[(size_t)(512 + kb + e) * 4096 + ncol];
  ((half8*)wpack)[s] = v;
}

// ---------------- generic f16 MFMA GEMM: C = A[MxK] * Bt[NxK]^T + bias ----------------
template <typename OT>
__global__ __launch_bounds__(256) void gemm_f16(const f16* __restrict__ A,
                                                const f16* __restrict__ Bt,
                                                const float* __restrict__ bias,
                                                OT* __restrict__ C,
                                                int M, int N, int K) {
  __shared__ __align__(16) char smem[32768];   // As 16K | Bs 16K
  const int tid = threadIdx.x;
  const int n0 = blockIdx.x * 128, m0 = blockIdx.y * 128;
  const int l = tid & 63, w = tid >> 6;
  const int wr = w >> 1, wc = w & 1;
  const int r16 = l & 15, hi = l >> 4;
  floatx4 acc[4][4];
#pragma unroll
  for (int a = 0; a < 4; ++a)
#pragma unroll
    for (int b = 0; b < 4; ++b) acc[a][b] = (floatx4){0.f, 0.f, 0.f, 0.f};

  const int nk = K >> 6;
  for (int kk = 0; kk < nk; ++kk) {
    __syncthreads();
#pragma unroll
    for (int q = 0; q < 4; ++q) {
      int c = q * 256 + tid;
      int row = c >> 3, g8 = c & 7;
      gload_lds16(A + (size_t)(m0 + row) * K + kk * 64 + g8 * 8, smem + c * 16);
    }
#pragma unroll
    for (int q = 0; q < 4; ++q) {
      int c = q * 256 + tid;
      int row = c >> 3, g8 = c & 7;
      gload_lds16(Bt + (size_t)(n0 + row) * K + kk * 64 + g8 * 8, smem + 16384 + c * 16);
    }
    __syncthreads();
#pragma unroll
    for (int ks = 0; ks < 2; ++ks) {
      half8 af[4], bf[4];
#pragma unroll
      for (int mi = 0; mi < 4; ++mi)
        af[mi] = *(const half8*)(smem + ((wr * 64 + mi * 16 + r16) * 64 + ks * 32 + hi * 8) * 2);
#pragma unroll
      for (int ni = 0; ni < 4; ++ni)
        bf[ni] = *(const half8*)(smem + 16384 +
                                 ((wc * 64 + ni * 16 + r16) * 64 + ks * 32 + hi * 8) * 2);
#pragma unroll
      for (int mi = 0; mi < 4; ++mi)
#pragma unroll
        for (int ni = 0; ni < 4; ++ni)
          acc[mi][ni] = __builtin_amdgcn_mfma_f32_16x16x32_f16(af[mi], bf[ni], acc[mi][ni], 0, 0, 0);
    }
  }
#pragma unroll
  for (int ni = 0; ni < 4; ++ni) {
    int col = n0 + wc * 64 + ni * 16 + r16;
    float bv = bias[col];
#pragma unroll
    for (int mi = 0; mi < 4; ++mi)
#pragma unroll
      for (int rr = 0; rr < 4; ++rr) {
        int row = m0 + wr * 64 + mi * 16 + hi * 4 + rr;
        C[(size_t)row * N + col] = (OT)(acc[mi][ni][rr] + bv);
      }
  }
}

// ---------------- phase 2: persistent recurrent kernel ----------------
// grid 256 blocks x 512 threads. block bk: team = bk>>5 (16 batch rows),
// colblock cb = bk&31 (hidden units u0..u0+31 -> gate cols {g*1024+u0+ul}).
// wave w: ksl = w>>1 (K slice of 256 units), nh = w&1 (64-col half).
// Per-team h buffer: [3 bufs][4 slices][16 rows][256 units] f16 (16384 elems/buf).
// LDS h: slice-major granules S = ksl*512 + row*32 + qs; slot qs holds logical
// 8-unit group q = qs ^ (row&7) (bank swizzle).
__global__ __launch_bounds__(512, 2)
void lstm_phase2(const f16* __restrict__ wpack, const f16* __restrict__ xw,
                 const float* __restrict__ c_in, const float* __restrict__ h_in,
                 const int* __restrict__ seq_lens,
                 f16* teamh_all, unsigned* flags,
                 float* __restrict__ lstm_out, f16* __restrict__ lstm16,
                 float* __restrict__ c_out, float* __restrict__ h_out) {
  __shared__ __align__(16) char smem[65536];   // h slices 32K | red 32K (XOR-swizzled)
  const int tid = threadIdx.x;
  const int bk = blockIdx.x;
  const int team = bk >> 5, cb = bk & 31;
  const int b0 = team * 16;
  const int u0 = cb * 32;
  const int l = tid & 63, w = tid >> 6;
  const int nh = w & 1, ksl = w >> 1;
  const int r16 = l & 15, hi = l >> 4;

  // persistent W_h fragments: 32 x f16x8 = 128 VGPRs
  half8 wf[4][8];
  {
    const half8* wp = (const half8*)wpack;
    size_t base = (size_t)((cb * 8 + w) * 4) * 8 * 64;
#pragma unroll
    for (int ni = 0; ni < 4; ++ni)
#pragma unroll
      for (int ks = 0; ks < 8; ++ks)
        wf[ni][ks] = wp[base + (size_t)(ni * 8 + ks) * 64 + l];
  }

  const int bb = tid >> 5, ul = tid & 31;     // consumer identity: batch row, unit
  const int bglob = b0 + bb;
  const int nunit = u0 + ul;
  float creg = c_in[bglob * 1024 + nunit];
  float hreg = h_in[bglob * 1024 + nunit];
  const int slen = seq_lens[bglob];

  float* red = (float*)(smem + 32768);
  f16* teamh = teamh_all + (size_t)team * 3 * 16384;
  unsigned* wflag = flags + (size_t)(team * 32 + cb) * 8 + w;      // this wave's flag
  const unsigned* pollp = flags + (size_t)team * 256 + ksl * 64 + l; // 64 producer waves

  // producer store offset (slice-major): slice cb>>3, row bb, units (cb&7)*32+ul
  const int hsto = (cb >> 3) * 4096 + bb * 256 + (cb & 7) * 32 + ul;

  int rb = 0;                              // t % 3
#pragma unroll 1
  for (int t = 0; t < 512; ++t) {
    const int wb = (rb == 2) ? 0 : rb + 1; // (t+1) % 3

    // x-projection for this step (plain cached loads; consumed at reduce)
    f16 xwv0, xwv1, xwv2, xwv3;
    {
      const f16* xp = xw + ((size_t)bglob * 512 + t) * 4096 + nunit;
      xwv0 = xp[0]; xwv1 = xp[1024]; xwv2 = xp[2048]; xwv3 = xp[3072];
    }

    if (t > 0) {
      // 64-lane poll: lane l watches producer wave (block ksl*8+(l>>3), wave l&7)
      while (true) {
        int g = load_flag_coh(pollp);
        if (__all(g >= t)) break;
      }
      asm volatile("" ::: "memory");
      // per-wave stage: 8 rows x 256 units (4KB) of slice ksl, contiguous source
      const char* hb = (const char*)(teamh + (size_t)rb * 16384);
#pragma unroll
      for (int j = 0; j < 4; ++j) {
        int rj = nh * 8 + 2 * j + (l >> 5);
        int ql = (l & 31) ^ (rj & 7);
        gload_lds16_coh(hb + (size_t)(ksl * 4096 + rj * 256 + ql * 8) * 2,
                        smem + (ksl * 512 + (nh * 8 + 2 * j) * 32) * 16);
      }
    } else {
      // first step: stage h_in (fp32 -> f16) into the same slice-major layout
#pragma unroll
      for (int j = 0; j < 4; ++j) {
        int idx = j * 512 + tid;            // storage granule 0..2047
        int ks_s = idx >> 9, rem = idx & 511, r = rem >> 5, qs = rem & 31;
        int ql = qs ^ (r & 7);
        const float* s = h_in + (size_t)(b0 + r) * 1024 + ks_s * 256 + ql * 8;
        half8 v;
#pragma unroll
        for (int e = 0; e < 8; ++e) v[e] = (f16)s[e];
        *(half8*)(smem + idx * 16) = v;
      }
    }
    __syncthreads();                     // bar D: all slices staged (drains vmcnt)

    // MFMA: gates_partial[16 x 64cols] over K slice of 256
    floatx4 acc0 = {0.f, 0.f, 0.f, 0.f}, acc1 = acc0, acc2 = acc0, acc3 = acc0;
#pragma unroll
    for (int ks = 0; ks < 8; ++ks) {
      int pq = (ks * 4 + hi) ^ (r16 & 7);       // swizzled slot -> conflict-free b128
      half8 a = *(const half8*)(smem + ksl * 8192 + r16 * 512 + pq * 16);
      acc0 = __builtin_amdgcn_mfma_f32_16x16x32_f16(a, wf[0][ks], acc0, 0, 0, 0);
      acc1 = __builtin_amdgcn_mfma_f32_16x16x32_f16(a, wf[1][ks], acc1, 0, 0, 0);
      acc2 = __builtin_amdgcn_mfma_f32_16x16x32_f16(a, wf[2][ks], acc2, 0, 0, 0);
      acc3 = __builtin_amdgcn_mfma_f32_16x16x32_f16(a, wf[3][ks], acc3, 0, 0, 0);
    }
    {
      int cbase = nh * 64 + r16;
      int rbase = ksl * 16 + hi * 4;
#pragma unroll
      for (int rr = 0; rr < 4; ++rr) {
        int rowr = rbase + rr;
        unsigned sw = (unsigned)(rowr & 7) << 2;   // bank XOR-swizzle
        float* rp = red + (size_t)rowr * 128;
        rp[(cbase + 0) ^ sw]  = acc0[rr];
        rp[(cbase + 16) ^ sw] = acc1[rr];
        rp[(cbase + 32) ^ sw] = acc2[rr];
        rp[(cbase + 48) ^ sw] = acc3[rr];
      }
    }
    __syncthreads();                     // bar G: red complete

    // reduce 4 K-slices + x-projection, then gate nonlinearities
    float g0 = (float)xwv0, g1 = (float)xwv1, g2 = (float)xwv2, g3 = (float)xwv3;
#pragma unroll
    for (int p = 0; p < 4; ++p) {
      int rowp = p * 16 + bb;
      unsigned sw = (unsigned)(rowp & 7) << 2;
      const float* rp = red + (size_t)rowp * 128;
      g0 += rp[(ul + 0) ^ sw];
      g1 += rp[(ul + 32) ^ sw];
      g2 += rp[(ul + 64) ^ sw];
      g3 += rp[(ul + 96) ^ sw];
    }
    float nc = creg * sigm(g2 + 1.f) + sigm(g0) * tanh_fast(g1);   // i,j,f,o order
    float nhv = tanh_fast(nc) * sigm(g3);
    bool valid = t < slen;
    if (valid) { creg = nc; hreg = nhv; }
    float outv = valid ? nhv : 0.f;
    size_t orow = ((size_t)bglob * 512 + t) * 1024 + nunit;

    // per-wave publish: coherent h store -> drain own stores -> plain flag store
    store_h_coh(teamh + (size_t)wb * 16384 + hsto, (f16)hreg);
    asm volatile("s_waitcnt vmcnt(0)" ::: "memory");
    if (l == 0) store_flag_coh(wflag, (unsigned)(t + 1));
    // bulk outputs: plain cached stores, AFTER the flag (off the critical path)
    lstm_out[orow] = outv;
    lstm16[orow] = (f16)outv;

    rb = wb;
  }

  c_out[bglob * 1024 + nunit] = creg;
  h_out[bglob * 1024 + nunit] = hreg;
}

// ---------------- host ----------------
extern "C" void kernel_launch(void* const* d_in, const int* in_sizes, int n_in,
                              void* d_out, int out_size, void* d_ws, size_t ws_size,
                              hipStream_t stream) {
  const float* inputs  = (const float*)d_in[0];
  const float* c_in    = (const float*)d_in[1];
  const float* h_in    = (const float*)d_in[2];
  const float* W_lstm  = (const float*)d_in[3];
  const float* b_lstm  = (const float*)d_in[4];
  const float* W_out   = (const float*)d_in[5];
  const float* b_out   = (const float*)d_in[6];
  const int*   seq_lens= (const int*)d_in[7];

  float* logits  = (float*)d_out;
  float* lstm_out= logits + (size_t)65536 * 256;
  float* c_out   = lstm_out + (size_t)65536 * 1024;
  float* h_out   = c_out + (size_t)128 * 1024;

  if (ws_size < WS_NEED) return;   // fail visibly (poison stays) rather than corrupt

  char* ws = (char*)d_ws;
  f16* xw    = (f16*)(ws + XW_OFF);
  f16* in16  = (f16*)(ws + IN16_OFF);
  f16* l16   = (f16*)(ws + L16_OFF);
  f16* wxt   = (f16*)(ws + WXT_OFF);
  f16* wot   = (f16*)(ws + WOT_OFF);
  f16* wpk   = (f16*)(ws + WPK_OFF);
  f16* teamh = (f16*)(ws + TH_OFF);
  unsigned* flags = (unsigned*)(ws + FLG_OFF);

  hipMemsetAsync(flags, 0, FLG_BY, stream);
  conv_f32_to_f16<<<16384, 256, 0, stream>>>(inputs, in16);
  transpose_f32_to_f16<<<dim3(64, 8), 256, 0, stream>>>(W_lstm, wxt, 512, 4096);
  transpose_f32_to_f16<<<dim3(4, 16), 256, 0, stream>>>(W_out, wot, 1024, 256);
  pack_wh<<<2048, 256, 0, stream>>>(W_lstm, wpk);

  // phase 1: xw = X @ W_x + b_lstm
  gemm_f16<f16><<<dim3(32, 512), 256, 0, stream>>>(in16, wxt, b_lstm, xw, 65536, 4096, 512);

  // phase 2: persistent recurrence (cooperative => co-residency guaranteed)
  {
    const f16* wpk_c = wpk;
    const f16* xw_c  = xw;
    void* args[] = {(void*)&wpk_c, (void*)&xw_c, (void*)&c_in, (void*)&h_in,
                    (void*)&seq_lens, (void*)&teamh, (void*)&flags,
                    (void*)&lstm_out, (void*)&l16, (void*)&c_out, (void*)&h_out};
    hipLaunchCooperativeKernel((void*)lstm_phase2, dim3(256), dim3(512), args, 0, stream);
  }

  // phase 3: logits = lstm_out @ W_out + b_out
  gemm_f16<float><<<dim3(2, 512), 256, 0, stream>>>(l16, wot, b_out, logits, 65536, 256, 1024);
}

// Round 6
// 3479.396 us; speedup vs baseline: 1.6408x; 1.0317x over previous
//
#include <hip/hip_runtime.h>

// ---------------------------------------------------------------------------
// LSTM (B=128, T=512, D=512, H=1024, O=256), forget bias 1.0
//   phase2 restructure (r6): swapped-operand MFMA puts all 4 gates of one
//   (unit,batch) in one lane's 4 acc regs -> no LDS reduction phase at all.
//   Poll never waits on unrelated VMEM (xw issued after poll barrier).
//   Publish: bulk -> coherent h -> vmcnt(0) -> per-wave plain flag store.
// ---------------------------------------------------------------------------

typedef _Float16 f16;
typedef _Float16 half8 __attribute__((ext_vector_type(8)));
typedef float floatx4 __attribute__((ext_vector_type(4)));
typedef unsigned u32x4 __attribute__((ext_vector_type(4)));

#define AS1 __attribute__((address_space(1)))
#define AS3 __attribute__((address_space(3)))

__device__ __forceinline__ void gload_lds16(const void* g, void* l) {
  __builtin_amdgcn_global_load_lds((const AS1 void*)g, (AS3 void*)l, 16, 0, 0);
}
// coherent (device-scope) variant: aux = SC0|SC1 = 1|16
__device__ __forceinline__ void gload_lds16_coh(const void* g, void* l) {
  __builtin_amdgcn_global_load_lds((const AS1 void*)g, (AS3 void*)l, 16, 0, 17);
}
__device__ __forceinline__ void store_flag_coh(unsigned* p, unsigned v) {
  asm volatile("global_store_dword %0, %1, off sc0 sc1" :: "v"(p), "v"(v) : "memory");
}
__device__ __forceinline__ void store_h_coh(f16* p, f16 v) {
  unsigned uv = (unsigned)__builtin_bit_cast(unsigned short, v);
  asm volatile("global_store_short %0, %1, off sc0 sc1" :: "v"(p), "v"(uv) : "memory");
}
__device__ __forceinline__ u32x4 load_flag4_coh(const unsigned* p) {
  u32x4 v;
  asm volatile("global_load_dwordx4 %0, %1, off sc0 sc1\n\ts_waitcnt vmcnt(0)"
               : "=v"(v) : "v"(p) : "memory");
  return v;
}

__device__ __forceinline__ float sigm(float x) { return 1.f / (1.f + __expf(-x)); }
__device__ __forceinline__ float tanh_fast(float x) {
  float ax = fabsf(x);
  float e = __expf(2.f * ax);          // overflows to +inf for big |x| -> t=1 exactly
  float t = 1.f - 2.f / (e + 1.f);
  return copysignf(t, x);
}

// ---------------- workspace layout ----------------
static constexpr size_t XW_OFF  = 0;
static constexpr size_t XW_BY   = (size_t)65536 * 4096 * 2;        // 536870912
static constexpr size_t L16_OFF = XW_OFF + XW_BY;                  // lstm_out f16 (aliases in16)
static constexpr size_t L16_BY  = (size_t)65536 * 1024 * 2;        // 134217728
static constexpr size_t IN16_OFF = L16_OFF;                        // inputs f16 (phase1 only)
static constexpr size_t WXT_OFF = L16_OFF + L16_BY;
static constexpr size_t WXT_BY  = (size_t)4096 * 512 * 2;
static constexpr size_t WOT_OFF = WXT_OFF + WXT_BY;
static constexpr size_t WOT_BY  = (size_t)256 * 1024 * 2;
static constexpr size_t WPK_OFF = WOT_OFF + WOT_BY;
static constexpr size_t WPK_BY  = (size_t)524288 * 8 * 2;          // W_h frag-packed
static constexpr size_t TH_OFF  = WPK_OFF + WPK_BY;
static constexpr size_t TH_BY   = (size_t)8 * 2 * 16 * 1024 * 2;   // h ping-pong per team
static constexpr size_t FLG_OFF = TH_OFF + TH_BY;
static constexpr size_t FLG_BY  = (size_t)8 * 256 * 4;             // flags[team][cb][wave]
static constexpr size_t WS_NEED = FLG_OFF + FLG_BY;

// ---------------- prep kernels ----------------
__global__ __launch_bounds__(256) void conv_f32_to_f16(const float* __restrict__ in,
                                                       f16* __restrict__ out) {
  size_t i = (size_t)blockIdx.x * 256 + threadIdx.x;
  const float4* in4 = (const float4*)in;
  float4 a = in4[i * 2], b = in4[i * 2 + 1];
  half8 v = {(f16)a.x, (f16)a.y, (f16)a.z, (f16)a.w,
             (f16)b.x, (f16)b.y, (f16)b.z, (f16)b.w};
  *(half8*)(out + i * 8) = v;
}

// out[c][r] = (f16)in[r][c]; grid = (C/64, R/64)
__global__ __launch_bounds__(256) void transpose_f32_to_f16(const float* __restrict__ in,
                                                            f16* __restrict__ out,
                                                            int R, int C) {
  __shared__ float tile[64][65];
  int tx = threadIdx.x & 63, ty = threadIdx.x >> 6;
  int c0 = blockIdx.x * 64, r0 = blockIdx.y * 64;
#pragma unroll
  for (int q = 0; q < 16; ++q) {
    int r = q * 4 + ty;
    tile[r][tx] = in[(size_t)(r0 + r) * C + c0 + tx];
  }
  __syncthreads();
#pragma unroll
  for (int q = 0; q < 16; ++q) {
    int oc = q * 4 + ty;
    out[(size_t)(c0 + oc) * R + r0 + tx] = (f16)tile[tx][oc];
  }
}

// Pack W_h (rows 512..1535 of W_lstm) as phase-2 MFMA A-operand fragments.
// m-map: m = lane&15 -> unit_local ul = m>>2, gate g = m&3; k = (lane>>4)*8+e.
// wpack[(((cb*8 + wv)*32) + ks)*64 + lane] : half8, element e =
//   W[512 + ks*32 + (lane>>4)*8 + e][g*1024 + cb*32 + wv*4 + ul]
__global__ __launch_bounds__(256) void pack_wh(const float* __restrict__ W,
                                               f16* __restrict__ wpack) {
  int s = blockIdx.x * 256 + threadIdx.x;   // 0 .. 524287
  int lane = s & 63;
  int ks = (s >> 6) & 31;
  int wv = (s >> 11) & 7;
  int cb = s >> 14;                          // 0..31
  int m = lane & 15;
  int ul = m >> 2, g = m & 3;
  int ncol = g * 1024 + cb * 32 + wv * 4 + ul;
  int kb = ks * 32 + (lane >> 4) * 8;
  half8 v;
#pragma unroll
  for (int e = 0; e < 8; ++e)
    v[e] = (f16)W[(size_t)(512 + kb + e) * 4096 + ncol];
  ((half8*)wpack)[s] = v;
}

// ---------------- generic f16 MFMA GEMM: C = A[MxK] * Bt[NxK]^T + bias ----------------
template <typename OT>
__global__ __launch_bounds__(256) void gemm_f16(const f16* __restrict__ A,
                                                const f16* __restrict__ Bt,
                                                const float* __restrict__ bias,
                                                OT* __restrict__ C,
                                                int M, int N, int K) {
  __shared__ __align__(16) char smem[32768];   // As 16K | Bs 16K
  const int tid = threadIdx.x;
  const int n0 = blockIdx.x * 128, m0 = blockIdx.y * 128;
  const int l = tid & 63, w = tid >> 6;
  const int wr = w >> 1, wc = w & 1;
  const int r16 = l & 15, hi = l >> 4;
  floatx4 acc[4][4];
#pragma unroll
  for (int a = 0; a < 4; ++a)
#pragma unroll
    for (int b = 0; b < 4; ++b) acc[a][b] = (floatx4){0.f, 0.f, 0.f, 0.f};

  const int nk = K >> 6;
  for (int kk = 0; kk < nk; ++kk) {
    __syncthreads();
#pragma unroll
    for (int q = 0; q < 4; ++q) {
      int c = q * 256 + tid;
      int row = c >> 3, g8 = c & 7;
      gload_lds16(A + (size_t)(m0 + row) * K + kk * 64 + g8 * 8, smem + c * 16);
    }
#pragma unroll
    for (int q = 0; q < 4; ++q) {
      int c = q * 256 + tid;
      int row = c >> 3, g8 = c & 7;
      gload_lds16(Bt + (size_t)(n0 + row) * K + kk * 64 + g8 * 8, smem + 16384 + c * 16);
    }
    __syncthreads();
#pragma unroll
    for (int ks = 0; ks < 2; ++ks) {
      half8 af[4], bf[4];
#pragma unroll
      for (int mi = 0; mi < 4; ++mi)
        af[mi] = *(const half8*)(smem + ((wr * 64 + mi * 16 + r16) * 64 + ks * 32 + hi * 8) * 2);
#pragma unroll
      for (int ni = 0; ni < 4; ++ni)
        bf[ni] = *(const half8*)(smem + 16384 +
                                 ((wc * 64 + ni * 16 + r16) * 64 + ks * 32 + hi * 8) * 2);
#pragma unroll
      for (int mi = 0; mi < 4; ++mi)
#pragma unroll
        for (int ni = 0; ni < 4; ++ni)
          acc[mi][ni] = __builtin_amdgcn_mfma_f32_16x16x32_f16(af[mi], bf[ni], acc[mi][ni], 0, 0, 0);
    }
  }
#pragma unroll
  for (int ni = 0; ni < 4; ++ni) {
    int col = n0 + wc * 64 + ni * 16 + r16;
    float bv = bias[col];
#pragma unroll
    for (int mi = 0; mi < 4; ++mi)
#pragma unroll
      for (int rr = 0; rr < 4; ++rr) {
        int row = m0 + wr * 64 + mi * 16 + hi * 4 + rr;
        C[(size_t)row * N + col] = (OT)(acc[mi][ni][rr] + bv);
      }
  }
}

// ---------------- phase 2: persistent recurrent kernel ----------------
// grid 256 x 512. block bk: team = bk>>5 (16 batch rows), cb = bk&31 (units
// u0..u0+31). wave w: units u0 + w*4 .. +3, full K=1024.
// MFMA per lane: acc regs = 4 gates of (unit = u0+w*4+(l>>4), batch = b0+(l&15)).
// h LDS [16 rows][128 granules], granule swizzle p = logical ^ (row&7).
__global__ __launch_bounds__(512, 1)
void lstm_phase2(const f16* __restrict__ wpack, const f16* __restrict__ xw,
                 const float* __restrict__ c_in, const float* __restrict__ h_in,
                 const int* __restrict__ seq_lens,
                 f16* teamh_all, unsigned* flags,
                 float* __restrict__ lstm_out, f16* __restrict__ lstm16,
                 float* __restrict__ c_out, float* __restrict__ h_out) {
  __shared__ __align__(16) char smem[34816];   // h 32K | tile 16x34 f16 (1088B)
  const int tid = threadIdx.x;
  const int bk = blockIdx.x;
  const int team = bk >> 5, cb = bk & 31;
  const int b0 = team * 16;
  const int u0 = cb * 32;
  const int l = tid & 63, w = tid >> 6;
  const int r16 = l & 15, hi = l >> 4;

  // persistent W fragments (A-operand), 32 x half8 = 128 VGPRs
  half8 wf[32];
  {
    const half8* wp = (const half8*)wpack;
    size_t base = (size_t)(cb * 8 + w) * 32 * 64;
#pragma unroll
    for (int k = 0; k < 32; ++k) wf[k] = wp[base + (size_t)k * 64 + l];
  }

  // compute identity
  const int bc = b0 + r16;              // batch row
  const int uloc = w * 4 + hi;          // block-local unit 0..31
  const int uc = u0 + uloc;             // hidden unit
  float creg = c_in[bc * 1024 + uc];
  float hreg = h_in[bc * 1024 + uc];
  const int slen_c = seq_lens[bc];
  const f16* xwb = xw + ((size_t)bc * 512) * 4096 + uc;

  // reader (batch-major) identity for publish/bulk
  const int b_r = tid >> 5, u_r = tid & 31;
  const int slen_r = seq_lens[b0 + b_r];
  f16* tile = (f16*)(smem + 32768);     // [16][34] f16, pad vs bank conflicts

  f16* teamh = teamh_all + (size_t)team * 32768;      // 2 bufs x 16x1024
  unsigned* tflags = flags + team * 256;
  unsigned* wflag = tflags + cb * 8 + w;
  const unsigned* pollp = tflags + l * 4;

#pragma unroll 1
  for (int t = 0; t < 512; ++t) {
    const int rb = t & 1, wb = rb ^ 1;
    f16 xw0, xw1, xw2, xw3;
    const f16* xp = xwb + (size_t)t * 4096;

    if (t > 0) {
      if (w != 0) {                    // issue xw during wave0's poll
        xw0 = xp[0]; xw1 = xp[1024]; xw2 = xp[2048]; xw3 = xp[3072];
      } else {                         // wave0: ONLY flag loads outstanding
        while (true) {
          u32x4 v = load_flag4_coh(pollp);
          bool ok = (int)v.x >= t && (int)v.y >= t && (int)v.z >= t && (int)v.w >= t;
          if (__all(ok)) break;
          __builtin_amdgcn_s_sleep(1);
        }
      }
      __syncthreads();                 // bar P: h(t) published team-wide
      const char* hb = (const char*)(teamh + (size_t)rb * 16384);
#pragma unroll
      for (int q = 0; q < 4; ++q) {
        int G = q * 512 + tid, r = G >> 7, p = G & 127, dg = p ^ (r & 7);
        gload_lds16_coh(hb + (size_t)(r * 1024 + dg * 8) * 2, smem + G * 16);
      }
      if (w == 0) { xw0 = xp[0]; xw1 = xp[1024]; xw2 = xp[2048]; xw3 = xp[3072]; }
    } else {
      xw0 = xp[0]; xw1 = xp[1024]; xw2 = xp[2048]; xw3 = xp[3072];
#pragma unroll
      for (int q = 0; q < 4; ++q) {
        int G = q * 512 + tid, r = G >> 7, p = G & 127, dg = p ^ (r & 7);
        const float* s = h_in + (size_t)(b0 + r) * 1024 + dg * 8;
        half8 v;
#pragma unroll
        for (int e = 0; e < 8; ++e) v[e] = (f16)s[e];
        *(half8*)(smem + G * 16) = v;
      }
    }
    __syncthreads();                   // bar D: h staged (drains gload + xw)

    // 32 MFMA over K=1024, 4 independent chains of 8
    floatx4 a0 = {0.f,0.f,0.f,0.f}, a1 = a0, a2 = a0, a3 = a0;
    const int sw = l & 7;
#pragma unroll
    for (int k = 0; k < 8; ++k) {
#define FR(K) (*(const half8*)(smem + r16 * 2048 + ((((K) * 4 + hi) ^ sw) * 16)))
      a0 = __builtin_amdgcn_mfma_f32_16x16x32_f16(wf[k],      FR(k),      a0, 0, 0, 0);
      a1 = __builtin_amdgcn_mfma_f32_16x16x32_f16(wf[8 + k],  FR(8 + k),  a1, 0, 0, 0);
      a2 = __builtin_amdgcn_mfma_f32_16x16x32_f16(wf[16 + k], FR(16 + k), a2, 0, 0, 0);
      a3 = __builtin_amdgcn_mfma_f32_16x16x32_f16(wf[24 + k], FR(24 + k), a3, 0, 0, 0);
#undef FR
    }
    floatx4 sacc = (a0 + a1) + (a2 + a3);   // acc[g]: g = i,j,f,o

    float gi = sacc[0] + (float)xw0;
    float gj = sacc[1] + (float)xw1;
    float gf = sacc[2] + (float)xw2;
    float go = sacc[3] + (float)xw3;
    float nc = creg * sigm(gf + 1.f) + sigm(gi) * tanh_fast(gj);
    float nhv = tanh_fast(nc) * sigm(go);
    if (t < slen_c) { creg = nc; hreg = nhv; }
    tile[r16 * 34 + uloc] = (f16)hreg;  // carried h -> batch-major transpose
    __syncthreads();                    // bar H

    // batch-major epilogue: bulk stores + coherent publish + per-wave flag
    f16 v16 = tile[b_r * 34 + u_r];
    bool valid_r = t < slen_r;
    size_t orow = ((size_t)(b0 + b_r) * 512 + t) * 1024 + u0 + u_r;
    lstm_out[orow] = valid_r ? (float)v16 : 0.f;
    lstm16[orow] = valid_r ? v16 : (f16)0;
    store_h_coh(teamh + (size_t)wb * 16384 + b_r * 1024 + u0 + u_r, v16);
    asm volatile("s_waitcnt vmcnt(0)" ::: "memory");   // all this wave's stores acked
    if (l == 0) store_flag_coh(wflag, (unsigned)(t + 1));
  }

  c_out[bc * 1024 + uc] = creg;
  h_out[bc * 1024 + uc] = hreg;
}

// ---------------- host ----------------
extern "C" void kernel_launch(void* const* d_in, const int* in_sizes, int n_in,
                              void* d_out, int out_size, void* d_ws, size_t ws_size,
                              hipStream_t stream) {
  const float* inputs  = (const float*)d_in[0];
  const float* c_in    = (const float*)d_in[1];
  const float* h_in    = (const float*)d_in[2];
  const float* W_lstm  = (const float*)d_in[3];
  const float* b_lstm  = (const float*)d_in[4];
  const float* W_out   = (const float*)d_in[5];
  const float* b_out   = (const float*)d_in[6];
  const int*   seq_lens= (const int*)d_in[7];

  float* logits  = (float*)d_out;
  float* lstm_out= logits + (size_t)65536 * 256;
  float* c_out   = lstm_out + (size_t)65536 * 1024;
  float* h_out   = c_out + (size_t)128 * 1024;

  if (ws_size < WS_NEED) return;   // fail visibly (poison stays) rather than corrupt

  char* ws = (char*)d_ws;
  f16* xw    = (f16*)(ws + XW_OFF);
  f16* in16  = (f16*)(ws + IN16_OFF);
  f16* l16   = (f16*)(ws + L16_OFF);
  f16* wxt   = (f16*)(ws + WXT_OFF);
  f16* wot   = (f16*)(ws + WOT_OFF);
  f16* wpk   = (f16*)(ws + WPK_OFF);
  f16* teamh = (f16*)(ws + TH_OFF);
  unsigned* flags = (unsigned*)(ws + FLG_OFF);

  hipMemsetAsync(flags, 0, FLG_BY, stream);
  conv_f32_to_f16<<<16384, 256, 0, stream>>>(inputs, in16);
  transpose_f32_to_f16<<<dim3(64, 8), 256, 0, stream>>>(W_lstm, wxt, 512, 4096);
  transpose_f32_to_f16<<<dim3(4, 16), 256, 0, stream>>>(W_out, wot, 1024, 256);
  pack_wh<<<2048, 256, 0, stream>>>(W_lstm, wpk);

  // phase 1: xw = X @ W_x + b_lstm
  gemm_f16<f16><<<dim3(32, 512), 256, 0, stream>>>(in16, wxt, b_lstm, xw, 65536, 4096, 512);

  // phase 2: persistent recurrence (cooperative => co-residency guaranteed)
  {
    const f16* wpk_c = wpk;
    const f16* xw_c  = xw;
    void* args[] = {(void*)&wpk_c, (void*)&xw_c, (void*)&c_in, (void*)&h_in,
                    (void*)&seq_lens, (void*)&teamh, (void*)&flags,
                    (void*)&lstm_out, (void*)&l16, (void*)&c_out, (void*)&h_out};
    hipLaunchCooperativeKernel((void*)lstm_phase2, dim3(256), dim3(512), args, 0, stream);
  }

  // phase 3: logits = lstm_out @ W_out + b_out
  gemm_f16<float><<<dim3(2, 512), 256, 0, stream>>>(l16, wot, b_out, logits, 65536, 256, 1024);
}